// Round 3
// baseline (877.910 us; speedup 1.0000x reference)
//
#include <hip/hip_runtime.h>
#include <math.h>

#define B_ 16
#define N_ 4096
#define D_ 64
#define K_ 8
#define H_ 4
#define HID_ 256
#define ITERS_ 3
#define EPS_ 1e-5f

// DH * (-0.5 * D * ln(2*pi)) = 16 * (-58.812066125099056)
#define HTERM_ (-940.9930580015849f)

__device__ __forceinline__ float waveReduceSum64(float v) {
  v += __shfl_xor(v, 1);  v += __shfl_xor(v, 2);  v += __shfl_xor(v, 4);
  v += __shfl_xor(v, 8);  v += __shfl_xor(v, 16); v += __shfl_xor(v, 32);
  return v;
}
__device__ __forceinline__ float groupReduceSum16(float v) {
  v += __shfl_xor(v, 1); v += __shfl_xor(v, 2); v += __shfl_xor(v, 4);
  v += __shfl_xor(v, 8);
  return v;
}

// DPP-based sum over each 16-lane row (result in all 16 lanes) — VALU pipe, no LDS.
template <int CTRL>
__device__ __forceinline__ float dpp_mov(float v) {
  return __int_as_float(__builtin_amdgcn_update_dpp(
      0, __float_as_int(v), CTRL, 0xF, 0xF, true));
}
__device__ __forceinline__ float row16Sum(float v) {
  v += dpp_mov<0xB1>(v);   // quad_perm(1,0,3,2)  : lane ^ 1
  v += dpp_mov<0x4E>(v);   // quad_perm(2,3,0,1)  : lane ^ 2
  v += dpp_mov<0x124>(v);  // row_ror:4
  v += dpp_mov<0x128>(v);  // row_ror:8
  return v;
}

// ---------- A: LayerNorm of embeddings -> x (local to chunk) ----------
__global__ void ln_emb_kernel(const float* __restrict__ emb,
                              const float* __restrict__ g, const float* __restrict__ b,
                              float* __restrict__ x, int b0) {
  int wave = threadIdx.x >> 6, lane = threadIdx.x & 63;
  int row = blockIdx.x * 4 + wave;                 // local row within chunk
  float e = emb[((size_t)b0 * N_ + row) * 64 + lane];
  float s  = waveReduceSum64(e);
  float sq = waveReduceSum64(e * e);
  float mean = s * (1.0f / 64.0f);
  float var  = sq * (1.0f / 64.0f) - mean * mean;
  float inv  = rsqrtf(var + EPS_);
  x[(size_t)row * 64 + lane] = (e - mean) * inv * g[lane] + b[lane];
}

// ---------- B: keys einsum  keys[bl,k,n,d] = sum_e x[bl,n,e]*Wk[k,e,d] ----------
__global__ __launch_bounds__(256) void key_kernel(const float* __restrict__ x,
    const float* __restrict__ Wk, float* __restrict__ keys) {
  __shared__ float xs[64 * 65];     // padded leading dim: column reads in compute
  __shared__ float wks[64 * 64];
  int n0 = blockIdx.x * 64;
  int k  = blockIdx.y;
  int bl = blockIdx.z;              // local b
  int tid = threadIdx.x;

  const float* xb = x + ((size_t)bl * N_ + n0) * 64;
  for (int i = tid; i < 4096; i += 256)
    xs[(i >> 6) * 65 + (i & 63)] = xb[i];
  const float4* wk4 = (const float4*)(Wk + (size_t)k * 4096);
  float4* wks4 = (float4*)wks;
  for (int i = tid; i < 1024; i += 256) wks4[i] = wk4[i];
  __syncthreads();

  int tr = tid >> 4, tc = tid & 15;
  int r0 = tr * 4, c0 = tc * 4;
  float ak[4][4] = {{0.f}};
  #pragma unroll 4
  for (int kk = 0; kk < 64; ++kk) {
    float xv[4];
    #pragma unroll
    for (int i = 0; i < 4; ++i) xv[i] = xs[(r0 + i) * 65 + kk];
    float4 wkq = *(const float4*)&wks[kk * 64 + c0];
    float wkc[4] = {wkq.x, wkq.y, wkq.z, wkq.w};
    #pragma unroll
    for (int i = 0; i < 4; ++i)
      #pragma unroll
      for (int j = 0; j < 4; ++j)
        ak[i][j] = fmaf(xv[i], wkc[j], ak[i][j]);
  }
  size_t outb = (((size_t)bl * K_ + k) * N_ + n0) * 64;
  #pragma unroll
  for (int i = 0; i < 4; ++i) {
    float4 kq = make_float4(ak[i][0], ak[i][1], ak[i][2], ak[i][3]);
    *(float4*)&keys[outb + (size_t)(r0 + i) * 64 + c0] = kq;
  }
}

// ---------- init: slots = mu + exp(lsig)*noise, sigma = exp(lsig), mixing ----------
__global__ void init_kernel(const float* __restrict__ mu, const float* __restrict__ lsig,
                            const float* __restrict__ mix0, const float* __restrict__ noise,
                            float* __restrict__ slots, float* __restrict__ sigma,
                            float* __restrict__ mixing, int b0) {
  int g = b0 * 512 + blockIdx.x * 256 + threadIdx.x;   // global b*K*D index
  int kd = g & 511;
  float sg = expf(lsig[kd]);
  slots[g] = mu[kd] + sg * noise[g];
  sigma[g] = sg;
  if ((g & 63) == 0) mixing[g >> 6] = mix0[(g >> 6) & (K_ - 1)];
}

// ---------- D: per-iteration prep: q, inv2s, base; zero accumulators ----------
__global__ void prep_kernel(const float* __restrict__ slots, const float* __restrict__ sigma,
                            const float* __restrict__ mixing, const float* __restrict__ tq,
                            const float* __restrict__ g_sl, const float* __restrict__ b_sl,
                            float* __restrict__ q, float* __restrict__ i2s,
                            float* __restrict__ base, float* __restrict__ S1,
                            float* __restrict__ S2, float* __restrict__ S0,
                            float* __restrict__ T, int b0) {
  int bk = b0 * K_ + blockIdx.x;               // global b*K index
  int lane = threadIdx.x;                      // 64 threads
  int k = bk & (K_ - 1);
  float s  = slots[bk * 64 + lane];
  float su = waveReduceSum64(s);
  float sq = waveReduceSum64(s * s);
  float mean = su * (1.0f / 64.0f);
  float var  = sq * (1.0f / 64.0f) - mean * mean;
  float sl = (s - mean) * rsqrtf(var + EPS_) * g_sl[lane] + b_sl[lane];
  q[bk * 64 + lane] = sl * tq[k * 4096 + lane * 65];   // diagonal of to_queries
  float sg = sigma[bk * 64 + lane];
  i2s[bk * 64 + lane] = 0.5f / (sg * sg + EPS_);
  float ls = -logf(fmaxf(sg, EPS_));
  float lss = groupReduceSum16(ls);
  if ((lane & 15) == 0)
    base[bk * 4 + (lane >> 4)] = logf(mixing[bk] + EPS_) + HTERM_ + lss;
  // zero this bk's accumulator slices
  S1[bk * 64 + lane] = 0.0f;
  S2[bk * 64 + lane] = 0.0f;
  T[bk * 256 + lane]       = 0.0f;
  T[bk * 256 + 64 + lane]  = 0.0f;
  T[bk * 256 + 128 + lane] = 0.0f;
  T[bk * 256 + 192 + lane] = 0.0f;
  if (lane < 4) S0[bk * 4 + lane] = 0.0f;
}

// ---------- C: attention pass (one read of keys + x; all moments incl. T) ----------
template <bool WRITE_ATTN>
__global__ __launch_bounds__(256, 4) void attn_kernel(
    const float* __restrict__ keys, const float* __restrict__ x,
    const float* __restrict__ q, const float* __restrict__ i2s, const float* __restrict__ base,
    float* __restrict__ S1, float* __restrict__ S2, float* __restrict__ S0,
    float* __restrict__ T, float* __restrict__ attn_out, int b0) {
  int bl = blockIdx.y;            // local b
  int bg = b0 + bl;               // global b
  int wave = threadIdx.x >> 6, lane = threadIdx.x & 63;
  int h = lane >> 4;
  int n0 = (blockIdx.x * 4 + wave) * 16;

  __shared__ float att_lds[4][K_][64];    // [wave][k][ni*4+h]
  __shared__ float blk[3104];             // S1 512 | S2 512 | T 2048 | S0 32
  for (int i = threadIdx.x; i < 3104; i += 256) blk[i] = 0.0f;

  float qv[K_], iv[K_], bv[K_];
  #pragma unroll
  for (int k = 0; k < K_; ++k) {
    int off = (bg * K_ + k) * 64 + lane;
    qv[k] = q[off];
    iv[k] = i2s[off];
    bv[k] = base[(bg * K_ + k) * 4 + h];
  }
  float s0a[K_] = {0.f}, s1a[K_] = {0.f}, s2a[K_] = {0.f};
  float xr[16];
  __syncthreads();

  const size_t bbase = (size_t)bl * K_ * N_ * 64;
  const float* xrow = x + ((size_t)bl * N_ + n0) * 64 + lane;
  // ---- phase 1: distances, softmax, key-moments; attn -> LDS ----
  #pragma unroll
  for (int ni = 0; ni < 16; ++ni) {
    int n = n0 + ni;
    float xv = xrow[(size_t)ni * 64];
    xr[ni] = xv;
    float key[K_], gl[K_];
    #pragma unroll
    for (int k = 0; k < K_; ++k)
      key[k] = keys[bbase + ((size_t)k * N_ + n) * 64 + lane];
    #pragma unroll
    for (int k = 0; k < K_; ++k) {
      float df = key[k] - qv[k];
      float t = row16Sum(df * df * iv[k]);   // sum over 16 dims of this head
      gl[k] = bv[k] - t;
    }
    float m = gl[0];
    #pragma unroll
    for (int k = 1; k < K_; ++k) m = fmaxf(m, gl[k]);
    float ssum = 0.f;
    #pragma unroll
    for (int k = 0; k < K_; ++k) { gl[k] = __expf(gl[k] - m); ssum += gl[k]; }
    float inv = __builtin_amdgcn_rcpf(ssum);
    #pragma unroll
    for (int k = 0; k < K_; ++k) {
      float a = gl[k] * inv + EPS_;          // attn (with +EPS, as in reference)
      s0a[k] += a;
      s1a[k] += a * key[k];
      s2a[k] = fmaf(a * key[k], key[k], s2a[k]);
      if ((lane & 15) == 0) att_lds[wave][k][ni * 4 + h] = a;
    }
  }
  // ---- phase 2: T[h][e] += sum_n a[n,h] * x[n][e]  (same-wave LDS, no barrier) ----
  #pragma unroll
  for (int k = 0; k < K_; ++k) {
    float t0 = 0.f, t1 = 0.f, t2 = 0.f, t3 = 0.f;
    #pragma unroll
    for (int ni = 0; ni < 16; ++ni) {
      float4 a4 = *(const float4*)&att_lds[wave][k][ni * 4];  // broadcast read
      float xv = xr[ni];
      t0 = fmaf(a4.x, xv, t0); t1 = fmaf(a4.y, xv, t1);
      t2 = fmaf(a4.z, xv, t2); t3 = fmaf(a4.w, xv, t3);
    }
    atomicAdd(&blk[1024 + k * 256 + lane],       t0);
    atomicAdd(&blk[1024 + k * 256 + 64 + lane],  t1);
    atomicAdd(&blk[1024 + k * 256 + 128 + lane], t2);
    atomicAdd(&blk[1024 + k * 256 + 192 + lane], t3);
  }
  // block-level LDS reduction of key-moments, then one global atomic per element
  #pragma unroll
  for (int k = 0; k < K_; ++k) {
    atomicAdd(&blk[k * 64 + lane],       s1a[k]);
    atomicAdd(&blk[512 + k * 64 + lane], s2a[k]);
    if ((lane & 15) == 0) atomicAdd(&blk[3072 + k * 4 + h], s0a[k]);
  }
  __syncthreads();
  for (int i = threadIdx.x; i < 512; i += 256) {
    atomicAdd(&S1[bg * 512 + i], blk[i]);
    atomicAdd(&S2[bg * 512 + i], blk[512 + i]);
  }
  for (int i = threadIdx.x; i < 2048; i += 256)
    atomicAdd(&T[bg * 2048 + i], blk[1024 + i]);
  if (threadIdx.x < 32) atomicAdd(&S0[bg * 32 + threadIdx.x], blk[3072 + threadIdx.x]);
  if (WRITE_ATTN) {
    #pragma unroll
    for (int k = 0; k < K_; ++k)
      attn_out[((size_t)(bg * K_ + k) * N_ + n0) * 4 + lane] = att_lds[wave][k][lane];
  }
}

// ---------- E: finalize moments -> sigma/mixing; GRU; LN; FFN; (final noise) ----------
__global__ __launch_bounds__(256) void update_kernel(
    const float* __restrict__ S1, const float* __restrict__ S2,
    const float* __restrict__ S0, const float* __restrict__ T,
    const float* __restrict__ Wv,
    float* __restrict__ slots, float* __restrict__ sigma, float* __restrict__ mixing,
    const float* __restrict__ w_ih, const float* __restrict__ w_hh,
    const float* __restrict__ b_ih, const float* __restrict__ b_hh,
    const float* __restrict__ w1, const float* __restrict__ b1,
    const float* __restrict__ w2, const float* __restrict__ b2,
    const float* __restrict__ g_ff, const float* __restrict__ b_ff,
    const float* __restrict__ noise_final, float* __restrict__ out_slots,
    int last, int b0) {
  int bk = b0 * K_ + blockIdx.x;
  int k = bk & (K_ - 1);
  int t = threadIdx.x;
  __shared__ float upd_s[64], sp_s[64], sig_s[64], xg_s[192], hg_s[192],
                   snew_s[64], pre_s[64], hid_s[256];
  if (t < 64) {
    float nk = S0[bk * 4 + 0] + S0[bk * 4 + 1] + S0[bk * 4 + 2] + S0[bk * 4 + 3];
    // Sv[d] = sum_e T[bk, h(d), e] * Wv[k, e, d]
    float sv = 0.f;
    const float* Trow = T + bk * 256 + (t >> 4) * 64;
    const float* wv = Wv + (size_t)k * 4096 + t;
    #pragma unroll 8
    for (int e = 0; e < 64; ++e) sv = fmaf(Trow[e], wv[(size_t)e * 64], sv);
    float upd = (1.0f / nk + EPS_) * sv;
    upd_s[t] = upd;
    float s1 = S1[bk * 64 + t], s2 = S2[bk * 64 + t], s0 = S0[bk * 4 + (t >> 4)];
    float sig2 = fmaxf(s2 - 2.0f * upd * s1 + upd * upd * s0, 0.0f);
    float sg = sqrtf(sig2 / nk) + EPS_;
    sigma[bk * 64 + t] = sg;
    sig_s[t] = sg;
    sp_s[t] = slots[bk * 64 + t];
    if (t == 0) mixing[bk] = nk / (float)N_;
  }
  __syncthreads();
  if (t < 192) {
    const float4* wr = (const float4*)(w_ih + t * 64);
    const float4* wh = (const float4*)(w_hh + t * 64);
    float a1 = b_ih[t], a2 = b_hh[t];
    #pragma unroll
    for (int d4 = 0; d4 < 16; ++d4) {
      float4 wa = wr[d4], wb = wh[d4];
      const float* u  = &upd_s[d4 * 4];
      const float* sp = &sp_s[d4 * 4];
      a1 += u[0] * wa.x + u[1] * wa.y + u[2] * wa.z + u[3] * wa.w;
      a2 += sp[0] * wb.x + sp[1] * wb.y + sp[2] * wb.z + sp[3] * wb.w;
    }
    xg_s[t] = a1;
    hg_s[t] = a2;
  }
  __syncthreads();
  if (t < 64) {
    float r = 1.0f / (1.0f + expf(-(xg_s[t] + hg_s[t])));
    float z = 1.0f / (1.0f + expf(-(xg_s[64 + t] + hg_s[64 + t])));
    float nn = tanhf(xg_s[128 + t] + r * hg_s[128 + t]);
    float sn = (1.0f - z) * nn + z * sp_s[t];
    snew_s[t] = sn;
    float su = waveReduceSum64(sn);
    float sq = waveReduceSum64(sn * sn);
    float mean = su * (1.0f / 64.0f);
    float var  = sq * (1.0f / 64.0f) - mean * mean;
    pre_s[t] = (sn - mean) * rsqrtf(var + EPS_) * g_ff[t] + b_ff[t];
  }
  __syncthreads();
  {
    const float4* w1r = (const float4*)(w1 + t * 64);
    float a = b1[t];
    #pragma unroll
    for (int d4 = 0; d4 < 16; ++d4) {
      float4 w = w1r[d4];
      const float* p = &pre_s[d4 * 4];
      a += p[0] * w.x + p[1] * w.y + p[2] * w.z + p[3] * w.w;
    }
    hid_s[t] = fmaxf(a, 0.0f);
  }
  __syncthreads();
  if (t < 64) {
    const float4* w2r = (const float4*)(w2 + t * 256);
    float a = b2[t];
    #pragma unroll
    for (int j4 = 0; j4 < 64; ++j4) {
      float4 w = w2r[j4];
      const float* p = &hid_s[j4 * 4];
      a += p[0] * w.x + p[1] * w.y + p[2] * w.z + p[3] * w.w;
    }
    float outv = snew_s[t] + a;
    slots[bk * 64 + t] = outv;
    if (last) out_slots[bk * 64 + t] = outv + sig_s[t] * noise_final[bk * 64 + t];
  }
}

extern "C" void kernel_launch(void* const* d_in, const int* in_sizes, int n_in,
                              void* d_out, int out_size, void* d_ws, size_t ws_size,
                              hipStream_t stream) {
  const float* emb  = (const float*)d_in[0];
  const float* mu   = (const float*)d_in[1];
  const float* lsig = (const float*)d_in[2];
  const float* mix0 = (const float*)d_in[3];
  const float* Wk   = (const float*)d_in[4];
  const float* Wq   = (const float*)d_in[5];
  const float* Wv   = (const float*)d_in[6];
  const float* w_ih = (const float*)d_in[7];
  const float* w_hh = (const float*)d_in[8];
  const float* b_ih = (const float*)d_in[9];
  const float* b_hh = (const float*)d_in[10];
  const float* w1   = (const float*)d_in[11];
  const float* b1   = (const float*)d_in[12];
  const float* w2   = (const float*)d_in[13];
  const float* b2   = (const float*)d_in[14];
  const float* g_in = (const float*)d_in[15];
  const float* b_in = (const float*)d_in[16];
  const float* g_sl = (const float*)d_in[17];
  const float* b_sl = (const float*)d_in[18];
  const float* g_ff = (const float*)d_in[19];
  const float* b_ff = (const float*)d_in[20];
  const float* nz0  = (const float*)d_in[21];
  const float* nzf  = (const float*)d_in[22];

  float* ws = (float*)d_ws;
  float* slots  = ws;                 // 8192  (full-B small buffers)
  float* sigma  = slots + 8192;       // 8192
  float* q      = sigma + 8192;       // 8192
  float* i2s    = q + 8192;           // 8192
  float* S1     = i2s + 8192;         // 8192
  float* S2     = S1 + 8192;          // 8192
  float* S0     = S2 + 8192;          // 512
  float* base   = S0 + 512;           // 512
  float* mixing = base + 512;         // 128
  float* T      = mixing + 128;       // 32768
  float* x      = T + 32768;          // C*N*64    (per-chunk)
  const size_t small_bytes = (size_t)(6 * 8192 + 512 + 512 + 128 + 32768) * 4;

  // largest chunk of batches whose x+keys fit in the workspace
  int C = 16;
  while (C > 1 && small_bytes + (size_t)C * 9437184ull > ws_size) C >>= 1;
  float* keys = x + (size_t)C * N_ * 64;

  float* out_slots = (float*)d_out;
  float* out_attn  = out_slots + B_ * K_ * 64;

  for (int b0 = 0; b0 < B_; b0 += C) {
    ln_emb_kernel<<<dim3(C * N_ / 4), 256, 0, stream>>>(emb, g_in, b_in, x, b0);
    key_kernel<<<dim3(N_ / 64, K_, C), 256, 0, stream>>>(x, Wk, keys);
    init_kernel<<<dim3(C * 2), 256, 0, stream>>>(mu, lsig, mix0, nz0, slots, sigma, mixing, b0);
    for (int it = 0; it < ITERS_; ++it) {
      prep_kernel<<<dim3(C * K_), 64, 0, stream>>>(slots, sigma, mixing, Wq, g_sl, b_sl,
                                                   q, i2s, base, S1, S2, S0, T, b0);
      if (it == ITERS_ - 1)
        attn_kernel<true><<<dim3(N_ / 64, C), 256, 0, stream>>>(keys, x, q, i2s, base,
                                                                S1, S2, S0, T, out_attn, b0);
      else
        attn_kernel<false><<<dim3(N_ / 64, C), 256, 0, stream>>>(keys, x, q, i2s, base,
                                                                 S1, S2, S0, T, nullptr, b0);
      update_kernel<<<dim3(C * K_), 256, 0, stream>>>(S1, S2, S0, T, Wv, slots, sigma, mixing,
          w_ih, w_hh, b_ih, b_hh, w1, b1, w2, b2, g_ff, b_ff, nzf, out_slots,
          it == ITERS_ - 1 ? 1 : 0, b0);
    }
  }
}

// Round 4
// 494.033 us; speedup vs baseline: 1.7770x; 1.7770x over previous
//
#include <hip/hip_runtime.h>
#include <math.h>

#define B_ 16
#define N_ 4096
#define D_ 64
#define K_ 8
#define H_ 4
#define HID_ 256
#define ITERS_ 3
#define EPS_ 1e-5f

// DH * (-0.5 * D * ln(2*pi)) = 16 * (-58.812066125099056)
#define HTERM_ (-940.9930580015849f)

__device__ __forceinline__ float waveReduceSum64(float v) {
  v += __shfl_xor(v, 1);  v += __shfl_xor(v, 2);  v += __shfl_xor(v, 4);
  v += __shfl_xor(v, 8);  v += __shfl_xor(v, 16); v += __shfl_xor(v, 32);
  return v;
}
__device__ __forceinline__ float groupReduceSum16(float v) {
  v += __shfl_xor(v, 1); v += __shfl_xor(v, 2); v += __shfl_xor(v, 4);
  v += __shfl_xor(v, 8);
  return v;
}

// DPP-based sum over each 16-lane row (result in all 16 lanes) — VALU pipe.
template <int CTRL>
__device__ __forceinline__ float dpp_mov(float v) {
  return __int_as_float(__builtin_amdgcn_update_dpp(
      0, __float_as_int(v), CTRL, 0xF, 0xF, true));
}
__device__ __forceinline__ float row16Sum(float v) {
  v += dpp_mov<0xB1>(v);   // quad_perm(1,0,3,2)  : lane ^ 1
  v += dpp_mov<0x4E>(v);   // quad_perm(2,3,0,1)  : lane ^ 2
  v += dpp_mov<0x124>(v);  // row_ror:4
  v += dpp_mov<0x128>(v);  // row_ror:8
  return v;
}

// ---------- A: LayerNorm of embeddings -> x (local to chunk) ----------
__global__ void ln_emb_kernel(const float* __restrict__ emb,
                              const float* __restrict__ g, const float* __restrict__ b,
                              float* __restrict__ x, int b0) {
  int wave = threadIdx.x >> 6, lane = threadIdx.x & 63;
  int row = blockIdx.x * 4 + wave;                 // local row within chunk
  float e = emb[((size_t)b0 * N_ + row) * 64 + lane];
  float s  = waveReduceSum64(e);
  float sq = waveReduceSum64(e * e);
  float mean = s * (1.0f / 64.0f);
  float var  = sq * (1.0f / 64.0f) - mean * mean;
  float inv  = rsqrtf(var + EPS_);
  x[(size_t)row * 64 + lane] = (e - mean) * inv * g[lane] + b[lane];
}

// ---------- B: keys einsum -> TRANSPOSED layout keys[bl][n][k][d] ----------
__global__ __launch_bounds__(256) void key_kernel(const float* __restrict__ x,
    const float* __restrict__ Wk, float* __restrict__ keys) {
  __shared__ float xs[64 * 65];     // padded leading dim: column reads in compute
  __shared__ float wks[64 * 64];
  int n0 = blockIdx.x * 64;
  int k  = blockIdx.y;
  int bl = blockIdx.z;              // local b
  int tid = threadIdx.x;

  const float* xb = x + ((size_t)bl * N_ + n0) * 64;
  for (int i = tid; i < 4096; i += 256)
    xs[(i >> 6) * 65 + (i & 63)] = xb[i];
  const float4* wk4 = (const float4*)(Wk + (size_t)k * 4096);
  float4* wks4 = (float4*)wks;
  for (int i = tid; i < 1024; i += 256) wks4[i] = wk4[i];
  __syncthreads();

  int tr = tid >> 4, tc = tid & 15;
  int r0 = tr * 4, c0 = tc * 4;
  float ak[4][4] = {{0.f}};
  #pragma unroll 4
  for (int kk = 0; kk < 64; ++kk) {
    float xv[4];
    #pragma unroll
    for (int i = 0; i < 4; ++i) xv[i] = xs[(r0 + i) * 65 + kk];
    float4 wkq = *(const float4*)&wks[kk * 64 + c0];
    float wkc[4] = {wkq.x, wkq.y, wkq.z, wkq.w};
    #pragma unroll
    for (int i = 0; i < 4; ++i)
      #pragma unroll
      for (int j = 0; j < 4; ++j)
        ak[i][j] = fmaf(xv[i], wkc[j], ak[i][j]);
  }
  // keys[((bl*N + n)*K + k)*64 + d]
  size_t outb = ((size_t)bl * N_ + n0) * 512 + (size_t)k * 64;
  #pragma unroll
  for (int i = 0; i < 4; ++i) {
    float4 kq = make_float4(ak[i][0], ak[i][1], ak[i][2], ak[i][3]);
    *(float4*)&keys[outb + (size_t)(r0 + i) * 512 + c0] = kq;
  }
}

// ---------- init: slots = mu + exp(lsig)*noise, sigma = exp(lsig), mixing ----------
__global__ void init_kernel(const float* __restrict__ mu, const float* __restrict__ lsig,
                            const float* __restrict__ mix0, const float* __restrict__ noise,
                            float* __restrict__ slots, float* __restrict__ sigma,
                            float* __restrict__ mixing, int b0) {
  int g = b0 * 512 + blockIdx.x * 256 + threadIdx.x;   // global b*K*D index
  int kd = g & 511;
  float sg = expf(lsig[kd]);
  slots[g] = mu[kd] + sg * noise[g];
  sigma[g] = sg;
  if ((g & 63) == 0) mixing[g >> 6] = mix0[(g >> 6) & (K_ - 1)];
}

// ---------- D: per-iteration prep: q, inv2s, base; zero accumulators ----------
__global__ void prep_kernel(const float* __restrict__ slots, const float* __restrict__ sigma,
                            const float* __restrict__ mixing, const float* __restrict__ tq,
                            const float* __restrict__ g_sl, const float* __restrict__ b_sl,
                            float* __restrict__ q, float* __restrict__ i2s,
                            float* __restrict__ base, float* __restrict__ S1,
                            float* __restrict__ S2, float* __restrict__ S0,
                            float* __restrict__ T, int b0) {
  int bk = b0 * K_ + blockIdx.x;               // global b*K index
  int lane = threadIdx.x;                      // 64 threads
  int k = bk & (K_ - 1);
  float s  = slots[bk * 64 + lane];
  float su = waveReduceSum64(s);
  float sq = waveReduceSum64(s * s);
  float mean = su * (1.0f / 64.0f);
  float var  = sq * (1.0f / 64.0f) - mean * mean;
  float sl = (s - mean) * rsqrtf(var + EPS_) * g_sl[lane] + b_sl[lane];
  q[bk * 64 + lane] = sl * tq[k * 4096 + lane * 65];   // diagonal of to_queries
  float sg = sigma[bk * 64 + lane];
  i2s[bk * 64 + lane] = 0.5f / (sg * sg + EPS_);
  float ls = -logf(fmaxf(sg, EPS_));
  float lss = groupReduceSum16(ls);
  if ((lane & 15) == 0)
    base[bk * 4 + (lane >> 4)] = logf(mixing[bk] + EPS_) + HTERM_ + lss;
  // zero this bk's accumulator slices
  S1[bk * 64 + lane] = 0.0f;
  S2[bk * 64 + lane] = 0.0f;
  T[bk * 256 + lane]       = 0.0f;
  T[bk * 256 + 64 + lane]  = 0.0f;
  T[bk * 256 + 128 + lane] = 0.0f;
  T[bk * 256 + 192 + lane] = 0.0f;
  if (lane < 4) S0[bk * 4 + lane] = 0.0f;
}

// ---------- C: attention pass. keys layout [bl][n][k][d]. Register-lean. ----------
template <bool WRITE_ATTN>
__global__ __launch_bounds__(256, 4) void attn_kernel(
    const float* __restrict__ keys, const float* __restrict__ x,
    const float* __restrict__ q, const float* __restrict__ i2s, const float* __restrict__ base,
    float* __restrict__ S1, float* __restrict__ S2, float* __restrict__ S0,
    float* __restrict__ T, float* __restrict__ attn_out, int b0) {
  int bl = blockIdx.y;            // local b
  int bg = b0 + bl;               // global b
  int wave = threadIdx.x >> 6, lane = threadIdx.x & 63;
  int h = lane >> 4;
  int n0 = (blockIdx.x * 4 + wave) * 16;

  __shared__ float att_lds[4][K_][64];    // [wave][k][ni*4+h]
  __shared__ float blk[3104];             // S1 512 | S2 512 | T 2048 | S0 32
  __shared__ float bv_lds[32];            // base[bg, k, h]
  for (int i = threadIdx.x; i < 3104; i += 256) blk[i] = 0.0f;
  if (threadIdx.x < 32) bv_lds[threadIdx.x] = base[bg * 32 + threadIdx.x];

  // qv/iv: one base address, K_ imm-offset loads each
  float qv[K_], iv[K_];
  {
    const float* qp = q + bg * 512 + lane;
    const float* ip = i2s + bg * 512 + lane;
    #pragma unroll
    for (int k = 0; k < K_; ++k) { qv[k] = qp[k * 64]; iv[k] = ip[k * 64]; }
  }
  float s1a[K_] = {0.f}, s2a[K_] = {0.f};
  __syncthreads();

  // ---- phase 1: distances, softmax, key-moments; attn -> LDS ----
  const float* kptr = keys + ((size_t)bl * N_ + n0) * 512 + lane;
  #pragma unroll 2
  for (int ni = 0; ni < 16; ++ni) {
    float key[K_], gl[K_];
    #pragma unroll
    for (int k = 0; k < K_; ++k) key[k] = kptr[k * 64];   // imm offsets, one base
    #pragma unroll
    for (int k = 0; k < K_; ++k) {
      float df = key[k] - qv[k];
      float t = row16Sum(df * df * iv[k]);   // sum over 16 dims of this head
      gl[k] = bv_lds[k * 4 + h] - t;         // LDS broadcast read
    }
    float m = gl[0];
    #pragma unroll
    for (int k = 1; k < K_; ++k) m = fmaxf(m, gl[k]);
    float ssum = 0.f;
    #pragma unroll
    for (int k = 0; k < K_; ++k) { gl[k] = __expf(gl[k] - m); ssum += gl[k]; }
    float inv = __builtin_amdgcn_rcpf(ssum);
    #pragma unroll
    for (int k = 0; k < K_; ++k) {
      float a = gl[k] * inv + EPS_;          // attn (with +EPS, as in reference)
      s1a[k] = fmaf(a, key[k], s1a[k]);
      s2a[k] = fmaf(a * key[k], key[k], s2a[k]);
      if ((lane & 15) == 0) att_lds[wave][k][ni * 4 + h] = a;
    }
    kptr += 512;
  }
  // flush key-moments to LDS now (frees 16 VGPRs for phase 2)
  #pragma unroll
  for (int k = 0; k < K_; ++k) {
    atomicAdd(&blk[k * 64 + lane],       s1a[k]);
    atomicAdd(&blk[512 + k * 64 + lane], s2a[k]);
  }

  // ---- phase 2: T[h][e] += sum_n a[n,h]*x[n][e]; S0 from att_lds ----
  float xr[16];
  {
    const float* xptr = x + ((size_t)bl * N_ + n0) * 64 + lane;
    #pragma unroll
    for (int ni = 0; ni < 16; ++ni) xr[ni] = xptr[ni * 64];  // imm offsets
  }
  #pragma unroll
  for (int k = 0; k < K_; ++k) {
    float t0 = 0.f, t1 = 0.f, t2 = 0.f, t3 = 0.f;
    float c0 = 0.f, c1 = 0.f, c2 = 0.f, c3 = 0.f;
    #pragma unroll
    for (int ni = 0; ni < 16; ++ni) {
      float4 a4 = *(const float4*)&att_lds[wave][k][ni * 4];  // broadcast read
      float xv = xr[ni];
      t0 = fmaf(a4.x, xv, t0); t1 = fmaf(a4.y, xv, t1);
      t2 = fmaf(a4.z, xv, t2); t3 = fmaf(a4.w, xv, t3);
      c0 += a4.x; c1 += a4.y; c2 += a4.z; c3 += a4.w;
    }
    atomicAdd(&blk[1024 + k * 256 + lane],       t0);
    atomicAdd(&blk[1024 + k * 256 + 64 + lane],  t1);
    atomicAdd(&blk[1024 + k * 256 + 128 + lane], t2);
    atomicAdd(&blk[1024 + k * 256 + 192 + lane], t3);
    if (lane == 0) {
      atomicAdd(&blk[3072 + k * 4 + 0], c0);
      atomicAdd(&blk[3072 + k * 4 + 1], c1);
      atomicAdd(&blk[3072 + k * 4 + 2], c2);
      atomicAdd(&blk[3072 + k * 4 + 3], c3);
    }
  }
  __syncthreads();
  // block -> global, one atomic per element
  for (int i = threadIdx.x; i < 512; i += 256) {
    atomicAdd(&S1[bg * 512 + i], blk[i]);
    atomicAdd(&S2[bg * 512 + i], blk[512 + i]);
  }
  for (int i = threadIdx.x; i < 2048; i += 256)
    atomicAdd(&T[bg * 2048 + i], blk[1024 + i]);
  if (threadIdx.x < 32) atomicAdd(&S0[bg * 32 + threadIdx.x], blk[3072 + threadIdx.x]);
  if (WRITE_ATTN) {
    #pragma unroll
    for (int k = 0; k < K_; ++k)
      attn_out[((size_t)(bg * K_ + k) * N_ + n0) * 4 + lane] = att_lds[wave][k][lane];
  }
}

// ---------- E: finalize moments -> sigma/mixing; GRU; LN; FFN; (final noise) ----------
__global__ __launch_bounds__(256) void update_kernel(
    const float* __restrict__ S1, const float* __restrict__ S2,
    const float* __restrict__ S0, const float* __restrict__ T,
    const float* __restrict__ Wv,
    float* __restrict__ slots, float* __restrict__ sigma, float* __restrict__ mixing,
    const float* __restrict__ w_ih, const float* __restrict__ w_hh,
    const float* __restrict__ b_ih, const float* __restrict__ b_hh,
    const float* __restrict__ w1, const float* __restrict__ b1,
    const float* __restrict__ w2, const float* __restrict__ b2,
    const float* __restrict__ g_ff, const float* __restrict__ b_ff,
    const float* __restrict__ noise_final, float* __restrict__ out_slots,
    int last, int b0) {
  int bk = b0 * K_ + blockIdx.x;
  int k = bk & (K_ - 1);
  int t = threadIdx.x;
  __shared__ float upd_s[64], sp_s[64], sig_s[64], xg_s[192], hg_s[192],
                   snew_s[64], pre_s[64], hid_s[256];
  if (t < 64) {
    float nk = S0[bk * 4 + 0] + S0[bk * 4 + 1] + S0[bk * 4 + 2] + S0[bk * 4 + 3];
    // Sv[d] = sum_e T[bk, h(d), e] * Wv[k, e, d]
    float sv = 0.f;
    const float* Trow = T + bk * 256 + (t >> 4) * 64;
    const float* wv = Wv + (size_t)k * 4096 + t;
    #pragma unroll 8
    for (int e = 0; e < 64; ++e) sv = fmaf(Trow[e], wv[(size_t)e * 64], sv);
    float upd = (1.0f / nk + EPS_) * sv;
    upd_s[t] = upd;
    float s1 = S1[bk * 64 + t], s2 = S2[bk * 64 + t], s0 = S0[bk * 4 + (t >> 4)];
    float sig2 = fmaxf(s2 - 2.0f * upd * s1 + upd * upd * s0, 0.0f);
    float sg = sqrtf(sig2 / nk) + EPS_;
    sigma[bk * 64 + t] = sg;
    sig_s[t] = sg;
    sp_s[t] = slots[bk * 64 + t];
    if (t == 0) mixing[bk] = nk / (float)N_;
  }
  __syncthreads();
  if (t < 192) {
    const float4* wr = (const float4*)(w_ih + t * 64);
    const float4* wh = (const float4*)(w_hh + t * 64);
    float a1 = b_ih[t], a2 = b_hh[t];
    #pragma unroll
    for (int d4 = 0; d4 < 16; ++d4) {
      float4 wa = wr[d4], wb = wh[d4];
      const float* u  = &upd_s[d4 * 4];
      const float* sp = &sp_s[d4 * 4];
      a1 += u[0] * wa.x + u[1] * wa.y + u[2] * wa.z + u[3] * wa.w;
      a2 += sp[0] * wb.x + sp[1] * wb.y + sp[2] * wb.z + sp[3] * wb.w;
    }
    xg_s[t] = a1;
    hg_s[t] = a2;
  }
  __syncthreads();
  if (t < 64) {
    float r = 1.0f / (1.0f + expf(-(xg_s[t] + hg_s[t])));
    float z = 1.0f / (1.0f + expf(-(xg_s[64 + t] + hg_s[64 + t])));
    float nn = tanhf(xg_s[128 + t] + r * hg_s[128 + t]);
    float sn = (1.0f - z) * nn + z * sp_s[t];
    snew_s[t] = sn;
    float su = waveReduceSum64(sn);
    float sq = waveReduceSum64(sn * sn);
    float mean = su * (1.0f / 64.0f);
    float var  = sq * (1.0f / 64.0f) - mean * mean;
    pre_s[t] = (sn - mean) * rsqrtf(var + EPS_) * g_ff[t] + b_ff[t];
  }
  __syncthreads();
  {
    const float4* w1r = (const float4*)(w1 + t * 64);
    float a = b1[t];
    #pragma unroll
    for (int d4 = 0; d4 < 16; ++d4) {
      float4 w = w1r[d4];
      const float* p = &pre_s[d4 * 4];
      a += p[0] * w.x + p[1] * w.y + p[2] * w.z + p[3] * w.w;
    }
    hid_s[t] = fmaxf(a, 0.0f);
  }
  __syncthreads();
  if (t < 64) {
    const float4* w2r = (const float4*)(w2 + t * 256);
    float a = b2[t];
    #pragma unroll
    for (int j4 = 0; j4 < 64; ++j4) {
      float4 w = w2r[j4];
      const float* p = &hid_s[j4 * 4];
      a += p[0] * w.x + p[1] * w.y + p[2] * w.z + p[3] * w.w;
    }
    float outv = snew_s[t] + a;
    slots[bk * 64 + t] = outv;
    if (last) out_slots[bk * 64 + t] = outv + sig_s[t] * noise_final[bk * 64 + t];
  }
}

extern "C" void kernel_launch(void* const* d_in, const int* in_sizes, int n_in,
                              void* d_out, int out_size, void* d_ws, size_t ws_size,
                              hipStream_t stream) {
  const float* emb  = (const float*)d_in[0];
  const float* mu   = (const float*)d_in[1];
  const float* lsig = (const float*)d_in[2];
  const float* mix0 = (const float*)d_in[3];
  const float* Wk   = (const float*)d_in[4];
  const float* Wq   = (const float*)d_in[5];
  const float* Wv   = (const float*)d_in[6];
  const float* w_ih = (const float*)d_in[7];
  const float* w_hh = (const float*)d_in[8];
  const float* b_ih = (const float*)d_in[9];
  const float* b_hh = (const float*)d_in[10];
  const float* w1   = (const float*)d_in[11];
  const float* b1   = (const float*)d_in[12];
  const float* w2   = (const float*)d_in[13];
  const float* b2   = (const float*)d_in[14];
  const float* g_in = (const float*)d_in[15];
  const float* b_in = (const float*)d_in[16];
  const float* g_sl = (const float*)d_in[17];
  const float* b_sl = (const float*)d_in[18];
  const float* g_ff = (const float*)d_in[19];
  const float* b_ff = (const float*)d_in[20];
  const float* nz0  = (const float*)d_in[21];
  const float* nzf  = (const float*)d_in[22];

  float* ws = (float*)d_ws;
  float* slots  = ws;                 // 8192  (full-B small buffers)
  float* sigma  = slots + 8192;       // 8192
  float* q      = sigma + 8192;       // 8192
  float* i2s    = q + 8192;           // 8192
  float* S1     = i2s + 8192;         // 8192
  float* S2     = S1 + 8192;          // 8192
  float* S0     = S2 + 8192;          // 512
  float* base   = S0 + 512;           // 512
  float* mixing = base + 512;         // 128
  float* T      = mixing + 128;       // 32768
  float* x      = T + 32768;          // C*N*64    (per-chunk)
  const size_t small_bytes = (size_t)(6 * 8192 + 512 + 512 + 128 + 32768) * 4;

  // largest chunk of batches whose x+keys fit in the workspace
  int C = 16;
  while (C > 1 && small_bytes + (size_t)C * 9437184ull > ws_size) C >>= 1;
  float* keys = x + (size_t)C * N_ * 64;

  float* out_slots = (float*)d_out;
  float* out_attn  = out_slots + B_ * K_ * 64;

  for (int b0 = 0; b0 < B_; b0 += C) {
    ln_emb_kernel<<<dim3(C * N_ / 4), 256, 0, stream>>>(emb, g_in, b_in, x, b0);
    key_kernel<<<dim3(N_ / 64, K_, C), 256, 0, stream>>>(x, Wk, keys);
    init_kernel<<<dim3(C * 2), 256, 0, stream>>>(mu, lsig, mix0, nz0, slots, sigma, mixing, b0);
    for (int it = 0; it < ITERS_; ++it) {
      prep_kernel<<<dim3(C * K_), 64, 0, stream>>>(slots, sigma, mixing, Wq, g_sl, b_sl,
                                                   q, i2s, base, S1, S2, S0, T, b0);
      if (it == ITERS_ - 1)
        attn_kernel<true><<<dim3(N_ / 64, C), 256, 0, stream>>>(keys, x, q, i2s, base,
                                                                S1, S2, S0, T, out_attn, b0);
      else
        attn_kernel<false><<<dim3(N_ / 64, C), 256, 0, stream>>>(keys, x, q, i2s, base,
                                                                 S1, S2, S0, T, nullptr, b0);
      update_kernel<<<dim3(C * K_), 256, 0, stream>>>(S1, S2, S0, T, Wv, slots, sigma, mixing,
          w_ih, w_hh, b_ih, b_hh, w1, b1, w2, b2, g_ff, b_ff, nzf, out_slots,
          it == ITERS_ - 1 ? 1 : 0, b0);
    }
  }
}